// Round 3
// baseline (207.621 us; speedup 1.0000x reference)
//
#include <hip/hip_runtime.h>
#include <math.h>

// Problem constants (fixed by setup_inputs): B=4096, T=512, Q=4
#define T_DIM 512
#define GAMMA_F 0.997f
#define EPS_F 1e-3f
// log2(0.997)
#define LOG2_GAMMA (-0.0043345907f)

typedef float v4f __attribute__((ext_vector_type(4)));   // native vector: ok for nontemporal builtins

__device__ __forceinline__ float inv_rescale_f(float x) {
    // sign(x) * (((sqrt(1 + 4*eps*(|x|+1+eps)) - 1) / (2*eps))^2 - 1), sign(0)=0
    float s = (x > 0.f) ? 1.f : ((x < 0.f) ? -1.f : 0.f);
    float sqrt_arg = 1.f + 4.f * EPS_F * (fabsf(x) + 1.f + EPS_F);
    float q = (sqrtf(sqrt_arg) - 1.f) * (1.f / (2.f * EPS_F));
    return s * (q * q - 1.f);
}

__device__ __forceinline__ float rescale_f(float x) {
    return copysignf(sqrtf(fabsf(x) + 1.f) - 1.f, x) + EPS_F * x;
}

// Each thread computes 4 consecutive t outputs (one float4-group of the T axis).
// Window positions t0..t0+7 are loaded once and shared across the 4 windows.
__global__ __launch_bounds__(256) void nstep_qloss_kernel(
    const float* __restrict__ cur_q,    // (B,T,4)
    const float* __restrict__ next_q,   // (B,T,4)
    const float* __restrict__ log_p,    // (B,T)
    const float* __restrict__ reward,   // (B,T,4)
    const float* __restrict__ is_done,  // (B,T)
    const float* __restrict__ mask,     // (B,T)
    float* __restrict__ out,            // (B,T,4)
    int nthreads)                       // B*T/4
{
    int tid = blockIdx.x * 256 + threadIdx.x;
    if (tid >= nthreads) return;

    int tg = tid & (T_DIM / 4 - 1);     // t-group within row: 0..127
    int t0 = tg << 2;                   // 0..508
    int rowBase = (tid >> 7) << 9;      // b * 512 (element index in (B,T))

    const v4f* mask4 = (const v4f*)mask;
    const v4f* done4 = (const v4f*)is_done;
    const v4f* lp4   = (const v4f*)log_p;
    const v4f* rew4  = (const v4f*)reward;   // one v4f per (b,t)
    const v4f* nq4   = (const v4f*)next_q;
    const v4f* cq4   = (const v4f*)cur_q;
    v4f* out4        = (v4f*)out;

    const bool atEnd = (t0 == T_DIM - 4);

    // ---- scalar arrays: lo = t0..t0+3, hi = t0+4..t0+7 (halo) ----
    int v0 = tid;                        // == (rowBase + t0) / 4
    int v1 = atEnd ? v0 : (v0 + 1);      // clamp halo at row end
    v4f mlo = mask4[v0], mhi = mask4[v1];
    v4f dlo = done4[v0], dhi = done4[v1];
    v4f plo = lp4[v0],   phi = lp4[v1];
    if (atEnd) { mhi = (v4f)(0.f); }     // invalidate halo (weights go to 0)

    // ---- reward window: 8 v4fs, clamped at row end (values masked out) ----
    int eb = rowBase + t0;
    v4f r[8];
    r[0] = rew4[eb + 0]; r[1] = rew4[eb + 1]; r[2] = rew4[eb + 2]; r[3] = rew4[eb + 3];
    {
        int hb = atEnd ? (rowBase + T_DIM - 1) : (eb + 4);
        int hs = atEnd ? 0 : 1;
        r[4] = rew4[hb];
        r[5] = rew4[hb + hs];
        r[6] = rew4[hb + 2 * hs];
        r[7] = rew4[hb + 3 * hs];
    }

    // ---- per-position scalars ----
    float mv[8]  = { mlo.x, mlo.y, mlo.z, mlo.w, mhi.x, mhi.y, mhi.z, mhi.w };
    float Lm[8];
    Lm[0] = mlo.x * (1.f - dlo.x) * plo.x;
    Lm[1] = mlo.y * (1.f - dlo.y) * plo.y;
    Lm[2] = mlo.z * (1.f - dlo.z) * plo.z;
    Lm[3] = mlo.w * (1.f - dlo.w) * plo.w;
    Lm[4] = mhi.x * (1.f - dhi.x) * phi.x;
    Lm[5] = mhi.y * (1.f - dhi.y) * phi.y;
    Lm[6] = mhi.z * (1.f - dhi.z) * phi.z;
    Lm[7] = mhi.w * (1.f - dhi.w) * phi.w;

    const float g1 = GAMMA_F;
    const float g2 = g1 * g1;
    const float g3 = g2 * g1;
    const float g4 = g2 * g2;
    const float gpow[5] = { 1.f, g1, g2, g3, g4 };

    float mhiA[4] = { mhi.x, mhi.y, mhi.z, mhi.w };
    float dhiA[4] = { dhi.x, dhi.y, dhi.z, dhi.w };

    // prefetch cur_q and next_q for the 4 outputs up-front (ILP)
    v4f cq[4];
    cq[0] = cq4[eb + 0]; cq[1] = cq4[eb + 1]; cq[2] = cq4[eb + 2]; cq[3] = cq4[eb + 3];
    v4f nq[4];
    int iClamp = rowBase + T_DIM - 1;
#pragma unroll
    for (int j = 0; j < 4; ++j) {
        int ii = atEnd ? iClamp : (eb + 4 + j);
        nq[j] = nq4[ii];
    }

    const float inv_num_q = 1.f / 3.f;

#pragma unroll
    for (int j = 0; j < 4; ++j) {
        // windowed sums: taps j..j+4
        float a0 = 0.f, a1 = 0.f, a2 = 0.f, a3 = 0.f, Ls = 0.f;
#pragma unroll
        for (int k = 0; k < 5; ++k) {
            float w = gpow[k] * mv[j + k];
            a0 = fmaf(w, r[j + k].x, a0);
            a1 = fmaf(w, r[j + k].y, a1);
            a2 = fmaf(w, r[j + k].z, a2);
            a3 = fmaf(w, r[j + k].w, a3);
            Ls = fmaf(gpow[k], Lm[j + k], Ls);
        }
        Ls *= GAMMA_F * inv_num_q;

        // next_term
        int i = atEnd ? (T_DIM - 1) : (t0 + 4 + j);
        float moi = atEnd ? mlo.w : mhiA[j];
        float doi = atEnd ? dlo.w : dhiA[j];
        float coeff = exp2f((float)i * LOG2_GAMMA);   // gamma^i (absolute idx, faithful)
        float g = coeff * moi * (1.f - doi);
        float nt0 = g * inv_rescale_f(nq[j].x);
        float nt1 = g * inv_rescale_f(nq[j].y);
        float nt2 = g * inv_rescale_f(nq[j].z);
        float nt3 = g * inv_rescale_f(nq[j].w);

        // q_w = {1, 0.5, 0, 2}; inv_qw = {1, 2, 0, 0.5}
        float tgt0 = rescale_f(a0 + nt0 + 1.0f * Ls);
        float tgt1 = rescale_f(a1 + nt1 + 2.0f * Ls);
        float tgt2 = rescale_f(a2 + nt2);
        float tgt3 = rescale_f(a3 + nt3 + 0.5f * Ls);

        float hm = 0.5f * mv[j];
        float d0 = cq[j].x - tgt0;
        float d1 = cq[j].y - tgt1;
        float d3 = cq[j].w - tgt3;
        v4f o;
        o.x = hm * d0 * d0;
        o.y = hm * 0.5f * d1 * d1;
        o.z = 0.f;                       // q_w[2] == 0
        o.w = hm * 2.0f * d3 * d3;
        __builtin_nontemporal_store(o, &out4[eb + j]);
    }
}

extern "C" void kernel_launch(void* const* d_in, const int* in_sizes, int n_in,
                              void* d_out, int out_size, void* d_ws, size_t ws_size,
                              hipStream_t stream) {
    const float* cur_q   = (const float*)d_in[0];
    const float* next_q  = (const float*)d_in[1];
    const float* log_p   = (const float*)d_in[2];
    const float* reward  = (const float*)d_in[3];
    const float* is_done = (const float*)d_in[4];
    const float* mask    = (const float*)d_in[5];
    float* out = (float*)d_out;

    int BT = in_sizes[2];               // B*T
    int nthreads = BT / 4;              // 4 t per thread
    int blocks = (nthreads + 255) / 256;
    hipLaunchKernelGGL(nstep_qloss_kernel, dim3(blocks), dim3(256), 0, stream,
                       cur_q, next_q, log_p, reward, is_done, mask, out, nthreads);
}

// Round 4
// 157.683 us; speedup vs baseline: 1.3167x; 1.3167x over previous
//
#include <hip/hip_runtime.h>
#include <math.h>

// Problem constants (fixed by setup_inputs): B=4096, T=512, Q=4
#define T_DIM 512
#define GAMMA_F 0.997f
#define EPS_F 1e-3f
// log2(0.997)
#define LOG2_GAMMA (-0.0043345907f)

typedef float v4f __attribute__((ext_vector_type(4)));

__device__ __forceinline__ float inv_rescale_f(float x) {
    // sign(x) * (((sqrt(1 + 4*eps*(|x|+1+eps)) - 1) / (2*eps))^2 - 1), sign(0)=0
    float s = (x > 0.f) ? 1.f : ((x < 0.f) ? -1.f : 0.f);
    float sqrt_arg = 1.f + 4.f * EPS_F * (fabsf(x) + 1.f + EPS_F);
    float q = (sqrtf(sqrt_arg) - 1.f) * (1.f / (2.f * EPS_F));
    return s * (q * q - 1.f);
}

__device__ __forceinline__ float rescale_f(float x) {
    return copysignf(sqrtf(fabsf(x) + 1.f) - 1.f, x) + EPS_F * x;
}

// One thread per (b,t) — lanes map to consecutive t => every access coalesced.
// All loads are unconditional (indices clamped, invalid taps zeroed by a
// select AFTER the load) so the compiler can batch ~22 loads in flight
// before the first waitcnt, instead of serializing on 20 VGPRs like R0.
__global__ __launch_bounds__(256) void nstep_qloss_kernel(
    const float* __restrict__ cur_q,    // (B,T,4)
    const float* __restrict__ next_q,   // (B,T,4)
    const float* __restrict__ log_p,    // (B,T)
    const float* __restrict__ reward,   // (B,T,4)
    const float* __restrict__ is_done,  // (B,T)
    const float* __restrict__ mask,     // (B,T)
    float* __restrict__ out,            // (B,T,4)
    int BT)
{
    int idx = blockIdx.x * 256 + threadIdx.x;
    if (idx >= BT) return;
    int t = idx & (T_DIM - 1);
    int base = idx - t;                 // b*T

    // clamped tap offsets (k = 0..4) and the next_q index i = min(t+4, 511)
    int s1 = (t + 1 < T_DIM) ? t + 1 : T_DIM - 1;
    int s2 = (t + 2 < T_DIM) ? t + 2 : T_DIM - 1;
    int s3 = (t + 3 < T_DIM) ? t + 3 : T_DIM - 1;
    int s4 = (t + 4 < T_DIM) ? t + 4 : T_DIM - 1;
    int o0 = idx;
    int o1 = base + s1, o2 = base + s2, o3 = base + s3, o4 = base + s4;

    const v4f* rew4 = (const v4f*)reward;
    const v4f* nq4  = (const v4f*)next_q;
    const v4f* cq4  = (const v4f*)cur_q;
    v4f* out4       = (v4f*)out;

    // ---- issue ALL loads up front, no control flow between them ----
    float m0 = mask[o0], m1 = mask[o1], m2 = mask[o2], m3 = mask[o3], m4 = mask[o4];
    float d0 = is_done[o0], d1 = is_done[o1], d2 = is_done[o2], d3 = is_done[o3], d4 = is_done[o4];
    float p0 = log_p[o0], p1 = log_p[o1], p2 = log_p[o2], p3 = log_p[o3], p4 = log_p[o4];
    v4f r0 = rew4[o0], r1 = rew4[o1], r2 = rew4[o2], r3 = rew4[o3], r4 = rew4[o4];
    v4f nq = nq4[o4];                   // next_q at i = s4 (always valid; faithful)
    v4f cq = cq4[o0];

    // validity of taps 1..4 (tap 0 always valid)
    float v1 = (t + 1 < T_DIM) ? 1.f : 0.f;
    float v2 = (t + 2 < T_DIM) ? 1.f : 0.f;
    float v3 = (t + 3 < T_DIM) ? 1.f : 0.f;
    float v4v = (t + 4 < T_DIM) ? 1.f : 0.f;

    const float g1 = GAMMA_F;
    const float g2 = g1 * g1;
    const float g3 = g2 * g1;
    const float g4 = g2 * g2;

    // per-tap weights (validity folded in)
    float w0 = m0;
    float w1 = v1 * g1 * m1;
    float w2 = v2 * g2 * m2;
    float w3 = v3 * g3 * m3;
    float w4 = v4v * g4 * m4;

    // reward_sum per q
    float a0 = w0 * r0.x; float a1 = w0 * r0.y; float a2 = w0 * r0.z; float a3 = w0 * r0.w;
    a0 = fmaf(w1, r1.x, a0); a1 = fmaf(w1, r1.y, a1); a2 = fmaf(w1, r1.z, a2); a3 = fmaf(w1, r1.w, a3);
    a0 = fmaf(w2, r2.x, a0); a1 = fmaf(w2, r2.y, a1); a2 = fmaf(w2, r2.z, a2); a3 = fmaf(w2, r2.w, a3);
    a0 = fmaf(w3, r3.x, a0); a1 = fmaf(w3, r3.y, a1); a2 = fmaf(w3, r3.z, a2); a3 = fmaf(w3, r3.w, a3);
    a0 = fmaf(w4, r4.x, a0); a1 = fmaf(w4, r4.y, a1); a2 = fmaf(w4, r4.z, a2); a3 = fmaf(w4, r4.w, a3);

    // log_p window sum (q-independent scalar): sum_k gamma^(k+1) * m*(1-d)*lp * valid
    float Ls = w0 * (1.f - d0) * p0;
    Ls = fmaf(w1, (1.f - d1) * p1, Ls);
    Ls = fmaf(w2, (1.f - d2) * p2, Ls);
    Ls = fmaf(w3, (1.f - d3) * p3, Ls);
    Ls = fmaf(w4, (1.f - d4) * p4, Ls);
    Ls *= GAMMA_F * (1.f / 3.f);        // extra gamma factor * inv_num_q

    // next_term: coeff = gamma^i (absolute index, faithful), i = s4
    float coeff = exp2f((float)s4 * LOG2_GAMMA);
    float g = coeff * m4 * (1.f - d4);
    float nt0 = g * inv_rescale_f(nq.x);
    float nt1 = g * inv_rescale_f(nq.y);
    float nt2 = g * inv_rescale_f(nq.z);
    float nt3 = g * inv_rescale_f(nq.w);

    // q_w = {1, 0.5, 0, 2}; inv_qw = {1, 2, 0, 0.5}
    float tgt0 = rescale_f(a0 + nt0 + 1.0f * Ls);
    float tgt1 = rescale_f(a1 + nt1 + 2.0f * Ls);
    float tgt2 = rescale_f(a2 + nt2);
    float tgt3 = rescale_f(a3 + nt3 + 0.5f * Ls);

    float hm = 0.5f * m0;
    float e0 = cq.x - tgt0;
    float e1 = cq.y - tgt1;
    float e3 = cq.w - tgt3;
    (void)tgt2;
    v4f o;
    o.x = hm * e0 * e0;
    o.y = hm * 0.5f * e1 * e1;
    o.z = 0.f;                          // q_w[2] == 0
    o.w = hm * 2.0f * e3 * e3;
    out4[idx] = o;
}

extern "C" void kernel_launch(void* const* d_in, const int* in_sizes, int n_in,
                              void* d_out, int out_size, void* d_ws, size_t ws_size,
                              hipStream_t stream) {
    const float* cur_q   = (const float*)d_in[0];
    const float* next_q  = (const float*)d_in[1];
    const float* log_p   = (const float*)d_in[2];
    const float* reward  = (const float*)d_in[3];
    const float* is_done = (const float*)d_in[4];
    const float* mask    = (const float*)d_in[5];
    float* out = (float*)d_out;

    int BT = in_sizes[2];               // B*T
    int blocks = (BT + 255) / 256;
    hipLaunchKernelGGL(nstep_qloss_kernel, dim3(blocks), dim3(256), 0, stream,
                       cur_q, next_q, log_p, reward, is_done, mask, out, BT);
}